// Round 2
// baseline (1530.281 us; speedup 1.0000x reference)
//
#include <hip/hip_runtime.h>
#include <math.h>

#define BATCH   256
#define MAXSTEP 200
#define NQ      1024
#define SM1     199            // MAX_STEP - 1
#define NROWS   (BATCH * SM1)  // 50944
#define RPB     4              // rows (waves) per block
#define NBLK    (NROWS / RPB)  // 12736 exact

typedef float v4f __attribute__((ext_vector_type(4)));

// One 64-lane wave per (b, s) row, s = 1..199.  Round-0 scan engine (32 waves/CU
// oversubscription = at roofline) + fused tail via last-wave-done:
//   - lane 0 writes p/a with agent-scope atomic stores (coherent point, XCD-safe)
//   - acq_rel agent-scope fetch_add on done[b]; the wave that reaches 199 has
//     acquire visibility of all stores and computes the per-student BCE mean
//     in-wave (deterministic order), then one atomicAdd into out[0].
// Tails overlap with remaining scan waves -> second dispatch eliminated.
__global__ __launch_bounds__(256) void k_fused(const float* __restrict__ pred,
                                               const float* __restrict__ batch,
                                               float* __restrict__ out,
                                               int* __restrict__ done) {
    int row  = blockIdx.x * RPB + (threadIdx.x >> 6);
    int lane = threadIdx.x & 63;
    int b = row / SM1;
    int i = row - b * SM1;   // 0..198
    int s = i + 1;           // 1..199

    const v4f* brow = (const v4f*)(batch + (size_t)(b * MAXSTEP + s) * (2 * NQ));

    int hq = -1;
    #pragma unroll
    for (int k = 0; k < 8; ++k) {
        v4f v = __builtin_nontemporal_load(brow + lane + 64 * k);
        float sm = (v[0] + v[1]) + (v[2] + v[3]);   // values are 0.0 / 1.0
        if (sm != 0.f) {                            // <=1 lane, ~1/8 iterations
            int j = 0;
            if (v[1] != 0.f) j = 1;
            if (v[2] != 0.f) j = 2;
            if (v[3] != 0.f) j = 3;
            hq = (lane + 64 * k) * 4 + j;
        }
    }
    // wave max-reduce (at most one lane has hq >= 0)
    #pragma unroll
    for (int off = 32; off > 0; off >>= 1)
        hq = max(hq, __shfl_xor(hq, off));

    int old = 0;
    if (lane == 0) {
        float p = (hq >= 0) ? pred[(size_t)(b * MAXSTEP + i) * NQ + (hq & (NQ - 1))] : 0.f;
        float a = (hq >= 0 && hq < NQ) ? 1.f : 0.f;
        __hip_atomic_store(&out[1 + row],         p, __ATOMIC_RELAXED, __HIP_MEMORY_SCOPE_AGENT);
        __hip_atomic_store(&out[1 + NROWS + row], a, __ATOMIC_RELAXED, __HIP_MEMORY_SCOPE_AGENT);
        // release: orders the two stores above before the counter bump
        old = __hip_atomic_fetch_add(&done[b], 1, __ATOMIC_ACQ_REL, __HIP_MEMORY_SCOPE_AGENT);
    }
    old = __shfl(old, 0);
    if (old != SM1 - 1) return;     // wave-uniform: only the 199th wave continues

    // ---- tail for student b, wave-wide (acquire above makes all p/a visible) ----
    const float* pp = out + 1 + b * SM1;
    const float* aa = out + 1 + NROWS + b * SM1;

    float p4[4], a4[4];
    int lastv = -1;
    #pragma unroll
    for (int r = 0; r < 4; ++r) {
        int idx = lane + 64 * r;
        float p = 0.f, a = 0.f;
        if (idx < SM1) {
            p = __hip_atomic_load(&pp[idx], __ATOMIC_RELAXED, __HIP_MEMORY_SCOPE_AGENT);
            a = __hip_atomic_load(&aa[idx], __ATOMIC_RELAXED, __HIP_MEMORY_SCOPE_AGENT);
        }
        p4[r] = p; a4[r] = a;
        if (p > 0.f) lastv = idx;   // p > 0 iff row valid
    }
    #pragma unroll
    for (int off = 32; off > 0; off >>= 1)
        lastv = max(lastv, __shfl_xor(lastv, off));

    float sum = 0.f;
    #pragma unroll
    for (int r = 0; r < 4; ++r) {
        int idx = lane + 64 * r;
        bool valid = (idx < SM1) && ((lastv < 0) || (idx <= lastv));
        if (valid) {
            float logp = fmaxf(logf(p4[r]), -100.f);
            float log1 = fmaxf(logf(1.f - p4[r]), -100.f);
            sum += -(a4[r] * logp + (1.f - a4[r]) * log1);
        }
    }
    #pragma unroll
    for (int off = 32; off > 0; off >>= 1)
        sum += __shfl_xor(sum, off);

    if (lane == 0) {
        float cntf = (lastv >= 0) ? (float)(lastv + 1) : (float)SM1;
        atomicAdd(out, sum / cntf);
    }
}

extern "C" void kernel_launch(void* const* d_in, const int* in_sizes, int n_in,
                              void* d_out, int out_size, void* d_ws, size_t ws_size,
                              hipStream_t stream) {
    const float* pred  = (const float*)d_in[0];
    const float* batch = (const float*)d_in[1];
    float* out  = (float*)d_out;
    int*   done = (int*)d_ws;

    hipMemsetAsync(d_out, 0, sizeof(float), stream);        // loss accumulator
    hipMemsetAsync(d_ws,  0, BATCH * sizeof(int), stream);  // per-student done counters
    k_fused<<<NBLK, 256, 0, stream>>>(pred, batch, out, done);
}

// Round 3
// 143.364 us; speedup vs baseline: 10.6741x; 10.6741x over previous
//
#include <hip/hip_runtime.h>
#include <math.h>

#define BATCH   256
#define MAXSTEP 200
#define NQ      1024
#define SM1     199            // MAX_STEP - 1
#define NROWS   (BATCH * SM1)  // 50944
#define RPB     4              // rows (waves) per block
#define NBLK    (NROWS / RPB)  // 12736 exact

typedef float v4f __attribute__((ext_vector_type(4)));

// One 64-lane wave per (b, s) row, s = 1..199 (round-0 scan engine, at the
// fabric roofline).  Key simplification: valid rows are a PREFIX (lengths>=2,
// zero-padded tails), and p>0 iff hq>=0, so the reference's trailing-trim mask
// is per-row independent: valid == (hq >= 0).  Lane 0 therefore computes the
// row's BCE locally and fire-and-forget accumulates into per-student S/C with
// plain device-scope relaxed atomicAdd (no fences, no cache ops -- the round-2
// acq_rel agent-scope RMW was the 20x regression).  Kernel boundary provides
// coherence for the tiny final kernel.
__global__ __launch_bounds__(256) void k_scan(const float* __restrict__ pred,
                                              const float* __restrict__ batch,
                                              float* __restrict__ out,
                                              float* __restrict__ S,
                                              int* __restrict__ C) {
    int row  = blockIdx.x * RPB + (threadIdx.x >> 6);
    int lane = threadIdx.x & 63;
    int b = row / SM1;
    int i = row - b * SM1;   // 0..198
    int s = i + 1;           // 1..199

    const v4f* brow = (const v4f*)(batch + (size_t)(b * MAXSTEP + s) * (2 * NQ));

    int hq = -1;
    #pragma unroll
    for (int k = 0; k < 8; ++k) {
        v4f v = __builtin_nontemporal_load(brow + lane + 64 * k);
        float sm = (v[0] + v[1]) + (v[2] + v[3]);   // values are 0.0 / 1.0
        if (sm != 0.f) {                            // <=1 lane, ~1/8 iterations
            int j = 0;
            if (v[1] != 0.f) j = 1;
            if (v[2] != 0.f) j = 2;
            if (v[3] != 0.f) j = 3;
            hq = (lane + 64 * k) * 4 + j;
        }
    }
    // wave max-reduce (at most one lane has hq >= 0)
    #pragma unroll
    for (int off = 32; off > 0; off >>= 1)
        hq = max(hq, __shfl_xor(hq, off));

    if (lane == 0) {
        float p = 0.f, a = 0.f;
        if (hq >= 0) {
            p = pred[(size_t)(b * MAXSTEP + i) * NQ + (hq & (NQ - 1))];
            a = (hq < NQ) ? 1.f : 0.f;
            float logp = fmaxf(logf(p), -100.f);
            float log1 = fmaxf(logf(1.f - p), -100.f);
            float bce  = -(a * logp + (1.f - a) * log1);
            atomicAdd(&S[b], bce);   // device-scope relaxed, no return -> no stall
            atomicAdd(&C[b], 1);
        }
        out[1 + row]         = p;   // prediction
        out[1 + NROWS + row] = a;   // ground_truth
    }
}

// One wave: loss = sum_b S[b]/C[b], deterministic tree order.
__global__ __launch_bounds__(64) void k_final(const float* __restrict__ S,
                                              const int* __restrict__ C,
                                              float* __restrict__ out) {
    int l = threadIdx.x;
    float acc = 0.f;
    #pragma unroll
    for (int k = 0; k < 4; ++k) {
        int idx = l + 64 * k;
        int c = C[idx];
        if (c > 0) acc += S[idx] / (float)c;   // c >= 1 always (lengths >= 2)
    }
    #pragma unroll
    for (int off = 32; off > 0; off >>= 1)
        acc += __shfl_xor(acc, off);
    if (l == 0) out[0] = acc;
}

extern "C" void kernel_launch(void* const* d_in, const int* in_sizes, int n_in,
                              void* d_out, int out_size, void* d_ws, size_t ws_size,
                              hipStream_t stream) {
    const float* pred  = (const float*)d_in[0];
    const float* batch = (const float*)d_in[1];
    float* out = (float*)d_out;
    float* S   = (float*)d_ws;                 // [256] per-student BCE sums
    int*   C   = (int*)((float*)d_ws + BATCH); // [256] per-student valid counts

    hipMemsetAsync(d_ws, 0, 2 * BATCH * sizeof(float), stream);
    k_scan<<<NBLK, 256, 0, stream>>>(pred, batch, out, S, C);
    k_final<<<1, 64, 0, stream>>>(S, C, out);
}

// Round 4
// 73.282 us; speedup vs baseline: 20.8821x; 1.9563x over previous
//
#include <hip/hip_runtime.h>
#include <math.h>

#define BATCH   256
#define MAXSTEP 200
#define NQ      1024
#define SM1     199            // MAX_STEP - 1
#define NROWS   (BATCH * SM1)  // 50944
#define RPB     4              // rows (waves) per block
#define NBLK    (NROWS / RPB)  // 12736 exact

typedef float v4f __attribute__((ext_vector_type(4)));

// One 64-lane wave per (b, s) row, s = 1..199 — the round-0 scan engine,
// measured at the per-CU streaming ceiling (10.1 B/cyc/CU ~= m13's 10).
// valid == (hq >= 0) per-row (prefix-validity, harness-verified round 3), so
// lane 0 computes the row's BCE locally and PLAIN-stores it to ws[row]
// (-1.0 = invalid). NO atomics / fences in the hot path: round 2's acq_rel
// fences (cache ops) and round 3's float-atomic CAS contention were 2x-20x
// regressions. Kernel boundary provides coherence for the tiny tail.
__global__ __launch_bounds__(256) void k_scan(const float* __restrict__ pred,
                                              const float* __restrict__ batch,
                                              float* __restrict__ out,
                                              float* __restrict__ ws) {
    int row  = blockIdx.x * RPB + (threadIdx.x >> 6);
    int lane = threadIdx.x & 63;
    int b = row / SM1;
    int i = row - b * SM1;   // 0..198
    int s = i + 1;           // 1..199

    if (threadIdx.x == 0 && blockIdx.x == 0) out[0] = 0.f;  // loss accumulator

    const v4f* brow = (const v4f*)(batch + (size_t)(b * MAXSTEP + s) * (2 * NQ));

    int hq = -1;
    #pragma unroll
    for (int k = 0; k < 8; ++k) {
        v4f v = __builtin_nontemporal_load(brow + lane + 64 * k);
        float sm = (v[0] + v[1]) + (v[2] + v[3]);   // values are 0.0 / 1.0
        if (sm != 0.f) {                            // <=1 lane, ~1/8 iterations
            int j = 0;
            if (v[1] != 0.f) j = 1;
            if (v[2] != 0.f) j = 2;
            if (v[3] != 0.f) j = 3;
            hq = (lane + 64 * k) * 4 + j;
        }
    }
    // wave max-reduce (at most one lane has hq >= 0)
    #pragma unroll
    for (int off = 32; off > 0; off >>= 1)
        hq = max(hq, __shfl_xor(hq, off));

    if (lane == 0) {
        float p = 0.f, a = 0.f, w = -1.f;           // w = bce, -1 marks invalid
        if (hq >= 0) {
            p = pred[(size_t)(b * MAXSTEP + i) * NQ + (hq & (NQ - 1))];
            a = (hq < NQ) ? 1.f : 0.f;
            float logp = fmaxf(logf(p), -100.f);
            float log1 = fmaxf(logf(1.f - p), -100.f);
            w = -(a * logp + (1.f - a) * log1);     // >= 0 always
        }
        out[1 + row]         = p;   // prediction
        out[1 + NROWS + row] = a;   // ground_truth
        ws[row] = w;                // plain store, no atomic
    }
}

// One wave per student: sum + count valid BCEs from ws (L2/LLC-warm),
// one low-contention atomicAdd of the per-student mean into out[0].
__global__ __launch_bounds__(64) void k_final(const float* __restrict__ ws,
                                              float* __restrict__ out) {
    int b    = blockIdx.x;
    int lane = threadIdx.x;

    float s = 0.f, c = 0.f;
    #pragma unroll
    for (int k = 0; k < 4; ++k) {
        int idx = lane + 64 * k;
        if (idx < SM1) {
            float w = ws[b * SM1 + idx];
            if (w >= 0.f) { s += w; c += 1.f; }
        }
    }
    #pragma unroll
    for (int off = 32; off > 0; off >>= 1) {
        s += __shfl_xor(s, off);
        c += __shfl_xor(c, off);
    }
    if (lane == 0 && c > 0.f)
        atomicAdd(out, s / c);
}

extern "C" void kernel_launch(void* const* d_in, const int* in_sizes, int n_in,
                              void* d_out, int out_size, void* d_ws, size_t ws_size,
                              hipStream_t stream) {
    const float* pred  = (const float*)d_in[0];
    const float* batch = (const float*)d_in[1];
    float* out = (float*)d_out;
    float* ws  = (float*)d_ws;   // [NROWS] per-row BCE (-1 = invalid row)

    k_scan<<<NBLK, 256, 0, stream>>>(pred, batch, out, ws);
    k_final<<<BATCH, 64, 0, stream>>>(ws, out);
}